// Round 2
// baseline (370.943 us; speedup 1.0000x reference)
//
#include <hip/hip_runtime.h>
#include <math.h>

#define N_NODES 50000
#define N_EDGES 800000
#define EP (N_EDGES + N_NODES)   // 850000 edges incl. self loops
#define NEG 0.2f
#define SCAN_BLOCKS 49           // ceil(50000/1024)
#define HB N_NODES               // nodes per head slice

typedef __attribute__((ext_vector_type(8))) short bf16x8;
typedef __attribute__((ext_vector_type(4))) float f32x4;
typedef __attribute__((ext_vector_type(2))) float f32x2;

// bf16 round-to-nearest-even from fp32
static __device__ __forceinline__ unsigned short bf16_rn(float f) {
    union { float f; unsigned int u; } v; v.f = f;
    unsigned int u = v.u;
    unsigned int r = (u + 0x7FFFu + ((u >> 16) & 1u)) >> 16;
    return (unsigned short)r;
}
// unpack 2 bf16 (packed in a dword) -> f32x2 {low, high}
static __device__ __forceinline__ f32x2 bf2_unpack(unsigned int u) {
    union { unsigned int i; float f; } a, b;
    a.i = u << 16; b.i = u & 0xFFFF0000u;
    return (f32x2){a.f, b.f};
}

// ---------------- CSR build ----------------

__global__ void k_hist(const int* __restrict__ ei, int* __restrict__ counts) {
    int e = blockIdx.x * 256 + threadIdx.x;
    if (e >= EP) return;
    int d = (e < N_EDGES) ? ei[N_EDGES + e] : (e - N_EDGES);
    atomicAdd(&counts[d], 1);
}

__global__ void k_scan_block(const int* __restrict__ counts, int* __restrict__ excl,
                             int* __restrict__ bsums) {
    __shared__ int wsum[4];
    int b = blockIdx.x, t = threadIdx.x;
    int lane = t & 63, w = t >> 6;
    int i0 = b * 1024 + t * 4;
    int v0 = (i0 + 0 < N_NODES) ? counts[i0 + 0] : 0;
    int v1 = (i0 + 1 < N_NODES) ? counts[i0 + 1] : 0;
    int v2 = (i0 + 2 < N_NODES) ? counts[i0 + 2] : 0;
    int v3 = (i0 + 3 < N_NODES) ? counts[i0 + 3] : 0;
    int s = v0 + v1 + v2 + v3;
    int incl = s;
    #pragma unroll
    for (int d = 1; d < 64; d <<= 1) {
        int u = __shfl_up(incl, d);
        if (lane >= d) incl += u;
    }
    if (lane == 63) wsum[w] = incl;
    __syncthreads();
    if (t == 0) {
        int run = 0;
        #pragma unroll
        for (int i = 0; i < 4; ++i) { int x = wsum[i]; wsum[i] = run; run += x; }
        bsums[b] = run;   // block total
    }
    __syncthreads();
    int base = wsum[w] + incl - s;   // exclusive prefix of this thread's chunk
    if (i0 + 0 < N_NODES) excl[i0 + 0] = base;
    if (i0 + 1 < N_NODES) excl[i0 + 1] = base + v0;
    if (i0 + 2 < N_NODES) excl[i0 + 2] = base + v0 + v1;
    if (i0 + 3 < N_NODES) excl[i0 + 3] = base + v0 + v1 + v2;
}

// scan_mid folded in: every block wave-scans the 49 block sums itself
__global__ void k_scan_add(int* __restrict__ row_ptr, const int* __restrict__ bsums) {
    __shared__ int soff;
    int b = blockIdx.x, t = threadIdx.x;
    if (t < 64) {
        int v = (t < SCAN_BLOCKS) ? bsums[t] : 0;
        int incl = v;
        #pragma unroll
        for (int d = 1; d < 64; d <<= 1) {
            int u = __shfl_up(incl, d);
            if (t >= d) incl += u;
        }
        if (t == b) soff = incl - v;   // exclusive prefix at block b
    }
    __syncthreads();
    int off = soff;
    int i0 = b * 1024 + t * 4;
    #pragma unroll
    for (int j = 0; j < 4; ++j)
        if (i0 + j < N_NODES) row_ptr[i0 + j] += off;
    if (b == 0 && t == 0) row_ptr[N_NODES] = EP;
}

__global__ void k_scatter(const int* __restrict__ ei, const int* __restrict__ row_ptr,
                          int* __restrict__ fill, int* __restrict__ colb) {
    int e = blockIdx.x * 256 + threadIdx.x;
    if (e >= EP) return;
    int s, d;
    if (e < N_EDGES) { s = ei[e]; d = ei[N_EDGES + e]; }
    else             { s = e - N_EDGES; d = s; }
    int pos = row_ptr[d] + atomicAdd(&fill[d], 1);
    colb[pos] = s;
}

// ---------------- W1 -> MFMA B-fragment order (pi-permuted), bf16 ----------------
__global__ void k_cvtWfrag(const float* __restrict__ W1, bf16x8* __restrict__ Wfrag) {
    int ft = blockIdx.x * 256 + threadIdx.x;   // 8192 frag-lanes
    int c = ft >> 10, rem = ft & 1023;
    int nt = rem >> 6, l = rem & 63;
    int n = (l & 15) * 16 + nt;
    int k0 = c * 32 + (l >> 4) * 8;
    bf16x8 f;
    #pragma unroll
    for (int j = 0; j < 8; ++j)
        f[j] = (short)bf16_rn(W1[(k0 + j) * 256 + n]);
    Wfrag[ft] = f;
}

// ---------------- Layer 1 GEMM via bf16 MFMA + fused attention logits ----------------
// Output layout CHANGED to head-major slices: xph[h][node][32ch] bf16, so that
// per-head aggregation has a 3.2MB working set (fits one XCD's 4MB L2).
// as1/ad1 stored transposed: as1T[h][node].
#define GM_GRID 782   // ceil(50000/64)
__global__ __launch_bounds__(256) void
k_gemm1m(const float* __restrict__ x, const bf16x8* __restrict__ Wfrag,
         unsigned short* __restrict__ xph,
         const float* __restrict__ asrc, const float* __restrict__ adst,
         float* __restrict__ as1T, float* __restrict__ ad1T) {
    __shared__ bf16x8 lds[1024];   // one chunk of B frags: 16 KB
    int t = threadIdx.x, l = t & 63, w = t >> 6;
    int rowbase = blockIdx.x * 64 + w * 16;
    int m = l & 15, kg = l >> 4;

    f32x4 acc[16];
    #pragma unroll
    for (int nt = 0; nt < 16; ++nt)
        acc[nt] = (f32x4){0.f, 0.f, 0.f, 0.f};

    int r0 = rowbase + m;
    if (r0 > N_NODES - 1) r0 = N_NODES - 1;   // clamp (results unused)
    const float4* x4 = (const float4*)x;

    for (int c = 0; c < 8; ++c) {
        __syncthreads();   // previous chunk's B reads done before overwrite
        const bf16x8* src = Wfrag + c * 1024;
        #pragma unroll
        for (int q = 0; q < 4; ++q)
            lds[q * 256 + t] = src[q * 256 + t];
        __syncthreads();

        int kb = (c * 32 + kg * 8) >> 2;       // float4 col index
        float4 xa0 = x4[r0 * 64 + kb], xb0 = x4[r0 * 64 + kb + 1];
        bf16x8 aF0;
        aF0[0] = (short)bf16_rn(xa0.x); aF0[1] = (short)bf16_rn(xa0.y);
        aF0[2] = (short)bf16_rn(xa0.z); aF0[3] = (short)bf16_rn(xa0.w);
        aF0[4] = (short)bf16_rn(xb0.x); aF0[5] = (short)bf16_rn(xb0.y);
        aF0[6] = (short)bf16_rn(xb0.z); aF0[7] = (short)bf16_rn(xb0.w);

        #pragma unroll
        for (int nt = 0; nt < 16; ++nt) {
            bf16x8 bF = lds[nt * 64 + l];
            acc[nt] = __builtin_amdgcn_mfma_f32_16x16x32_bf16(aF0, bF, acc[nt], 0, 0, 0);
        }
    }

    // epilogue: lane holds channels cbase*16 + nt (nt=0..15) of rows rq*4+reg
    int cbase = l & 15, rq = l >> 4;
    int head = cbase >> 1, hhalf = cbase & 1;   // 16-ch half within head
    float asV[16], adV[16];
    #pragma unroll
    for (int q = 0; q < 4; ++q) {
        float4 sa = ((const float4*)asrc)[cbase * 4 + q];
        float4 da = ((const float4*)adst)[cbase * 4 + q];
        asV[q * 4 + 0] = sa.x; asV[q * 4 + 1] = sa.y; asV[q * 4 + 2] = sa.z; asV[q * 4 + 3] = sa.w;
        adV[q * 4 + 0] = da.x; adV[q * 4 + 1] = da.y; adV[q * 4 + 2] = da.z; adV[q * 4 + 3] = da.w;
    }
    #pragma unroll
    for (int reg = 0; reg < 4; ++reg) {
        int gr = rowbase + rq * 4 + reg;
        unsigned int ob[8];
        float ps = 0.f, pd = 0.f;
        #pragma unroll
        for (int q = 0; q < 8; ++q) {
            float v0 = acc[2 * q][reg], v1 = acc[2 * q + 1][reg];
            ob[q] = (unsigned int)bf16_rn(v0) | ((unsigned int)bf16_rn(v1) << 16);
            ps = fmaf(v0, asV[2 * q], ps);     ps = fmaf(v1, asV[2 * q + 1], ps);
            pd = fmaf(v0, adV[2 * q], pd);     pd = fmaf(v1, adV[2 * q + 1], pd);
        }
        ps += __shfl_xor(ps, 1);
        pd += __shfl_xor(pd, 1);
        if (gr < N_NODES) {
            // head-major slice write: [head][node][32ch], this lane's 16-ch half
            uint4* dst = (uint4*)(xph + (head * HB + gr) * 32 + hhalf * 16);
            dst[0] = make_uint4(ob[0], ob[1], ob[2], ob[3]);
            dst[1] = make_uint4(ob[4], ob[5], ob[6], ob[7]);
            if (hhalf == 0) {
                as1T[head * HB + gr] = ps;
                ad1T[head * HB + gr] = pd;
            }
        }
    }
}

// ---------------- head-sliced layer-1 softmax-aggregate + ReLU + proj2 partial ----
// head = blockIdx.x & 7  ->  under round-robin block->XCD dispatch, all blocks of
// head h land on XCD h, so the gather working set (3.2MB slice + 0.2MB as1T) is
// L2-resident. Wave = (node, head); 8 edges/iter, 8 lanes x 4ch (uint2) per edge.
// Emits the per-head proj2 partial (post-ReLU dot with W2 rows) into hpart[n][h].
__global__ __launch_bounds__(256) void
k_aggh(const uint2* __restrict__ xph, const float* __restrict__ as1T,
       const float* __restrict__ ad1T, const int* __restrict__ row_ptr,
       const int* __restrict__ colb, const float* __restrict__ b1,
       const float* __restrict__ W2, float2* __restrict__ hpart) {
    int t = threadIdx.x, l = t & 63, w = t >> 6;
    int bid = blockIdx.x;
    int h = bid & 7;              // XCD-pinned head
    int ng = bid >> 3;            // node group 0..12499
    int n = ng * 4 + w;
    int o = l >> 3;               // edge slot 0..7
    int sub = l & 7;              // channel sub: ch = h*32 + sub*4 .. +3
    float adn = ad1T[h * HB + n];
    int start = row_ptr[n], end = row_ptr[n + 1];
    const float* asb = as1T + h * HB;
    const uint2* xb = xph + (size_t)h * (HB * 8);
    f32x2 accA = {0.f, 0.f}, accB = {0.f, 0.f};
    float den = 0.f;
    int j = start;
    for (; j + 8 <= end; j += 8) {
        int s = colb[j + o];
        float e = asb[s] + adn;
        e = (e > 0.f) ? e : NEG * e;
        float p = __expf(e);
        den += p;
        uint2 r = xb[s * 8 + sub];
        f32x2 q = {p, p};
        accA += q * bf2_unpack(r.x);
        accB += q * bf2_unpack(r.y);
    }
    if (j + o < end) {            // tail: exec-masked, inactive lanes skip loads
        int s = colb[j + o];
        float e = asb[s] + adn;
        e = (e > 0.f) ? e : NEG * e;
        float p = __expf(e);
        den += p;
        uint2 r = xb[s * 8 + sub];
        f32x2 q = {p, p};
        accA += q * bf2_unpack(r.x);
        accB += q * bf2_unpack(r.y);
    }
    // reduce across the 8 edge slots (p is uniform within an octet, so masks
    // 8/16/32 suffice for den too)
    #pragma unroll
    for (int m = 8; m < 64; m <<= 1) {
        accA[0] += __shfl_xor(accA[0], m);
        accA[1] += __shfl_xor(accA[1], m);
        accB[0] += __shfl_xor(accB[0], m);
        accB[1] += __shfl_xor(accB[1], m);
        den += __shfl_xor(den, m);
    }
    float inv = 1.f / den;
    float4 bv = ((const float4*)b1)[h * 8 + sub];
    float o0 = fmaxf(accA[0] * inv + bv.x, 0.f);
    float o1 = fmaxf(accA[1] * inv + bv.y, 0.f);
    float o2 = fmaxf(accB[0] * inv + bv.z, 0.f);
    float o3 = fmaxf(accB[1] * inv + bv.w, 0.f);
    // proj2 partial: W2 row-major (256,2), rows r0 = h*32 + sub*4
    const float4* W4 = (const float4*)W2;
    float4 wa = W4[h * 16 + sub * 2 + 0];   // rows r0, r0+1
    float4 wb = W4[h * 16 + sub * 2 + 1];   // rows r0+2, r0+3
    float d0 = o0 * wa.x + o1 * wa.z + o2 * wb.x + o3 * wb.z;
    float d1 = o0 * wa.y + o1 * wa.w + o2 * wb.y + o3 * wb.w;
    #pragma unroll
    for (int m = 1; m < 8; m <<= 1) {
        d0 += __shfl_xor(d0, m);
        d1 += __shfl_xor(d1, m);
    }
    if (l == 0) hpart[n * 8 + h] = (float2){d0, d1};
}

// ---------------- sum head partials -> xp2 / layer-2 logits ----------------
__global__ void k_post(const float2* __restrict__ hpart, const float* __restrict__ as2w,
                       const float* __restrict__ ad2w, float* __restrict__ xp2,
                       float* __restrict__ as2, float* __restrict__ ad2) {
    int n = blockIdx.x * 256 + threadIdx.x;
    if (n >= N_NODES) return;
    const float4* hp4 = (const float4*)(hpart + n * 8);
    float d0 = 0.f, d1 = 0.f;
    #pragma unroll
    for (int q = 0; q < 4; ++q) {
        float4 v = hp4[q];
        d0 += v.x + v.z;
        d1 += v.y + v.w;
    }
    xp2[2 * n] = d0;
    xp2[2 * n + 1] = d1;
    as2[n] = d0 * as2w[0] + d1 * as2w[1];
    ad2[n] = d0 * ad2w[0] + d1 * ad2w[1];
}

// ---------------- fused segment-softmax + aggregate, layer 2 (2 channels) ----------------
__global__ void k_agg2(const float* __restrict__ xp2, const float* __restrict__ as2,
                       const float* __restrict__ ad2, const int* __restrict__ row_ptr,
                       const int* __restrict__ colb, const float* __restrict__ b2,
                       float* __restrict__ out) {
    int t = threadIdx.x;
    int g = t >> 4, lane = t & 15;
    int n = blockIdx.x * 16 + g;
    int start = row_ptr[n], end = row_ptr[n + 1];
    float adn = ad2[n];
    float a0 = 0.f, a1 = 0.f, den = 0.f;
    for (int j = start + lane; j < end; j += 16) {
        int s = colb[j];
        float e = as2[s] + adn;
        e = (e > 0.f) ? e : NEG * e;
        float p = __expf(e);
        den += p;
        float2 xv = ((const float2*)xp2)[s];
        a0 = fmaf(p, xv.x, a0);
        a1 = fmaf(p, xv.y, a1);
    }
    #pragma unroll
    for (int m = 1; m < 16; m <<= 1) {
        a0 += __shfl_xor(a0, m);
        a1 += __shfl_xor(a1, m);
        den += __shfl_xor(den, m);
    }
    if (lane == 0) {
        out[2 * n] = a0 / den + b2[0];
        out[2 * n + 1] = a1 / den + b2[1];
    }
}

extern "C" void kernel_launch(void* const* d_in, const int* in_sizes, int n_in,
                              void* d_out, int out_size, void* d_ws, size_t ws_size,
                              hipStream_t stream) {
    const float* x     = (const float*)d_in[0];
    const int*   ei    = (const int*)d_in[1];
    const float* W1    = (const float*)d_in[2];
    const float* asrc1 = (const float*)d_in[3];
    const float* adst1 = (const float*)d_in[4];
    const float* b1    = (const float*)d_in[5];
    const float* W2    = (const float*)d_in[6];
    const float* asrc2 = (const float*)d_in[7];
    const float* adst2 = (const float*)d_in[8];
    const float* b2    = (const float*)d_in[9];
    float* out = (float*)d_out;

    char* ws = (char*)d_ws;
    unsigned short* xph = (unsigned short*)(ws + 0);  // 25,600,000 B (bf16, head-major)
    bf16x8* Wfrag  = (bf16x8*)(ws + 25600000);      //    131,072 B (B frags)
    float2* hpart  = (float2*)(ws + 25800000);      //  3,200,000 B (per-head proj2 partials)
    float* as1T    = (float*)(ws + 102400000);      //  1,600,000 B ([8][50000])
    float* ad1T    = (float*)(ws + 104000000);      //  1,600,000 B ([8][50000])
    float* xp2     = (float*)(ws + 105600000);      //    400,000 B
    float* as2     = (float*)(ws + 106000000);      //    200,000 B
    float* ad2     = (float*)(ws + 106200000);      //    200,000 B
    int*   counts  = (int*)  (ws + 106400000);      //    200,000 B
    int*   fill    = (int*)  (ws + 106600000);      //    200,000 B (contig w/ counts)
    int*   row_ptr = (int*)  (ws + 106800000);      //    200,064 B
    int*   colb    = (int*)  (ws + 107000064);      //  3,400,000 B
    int*   bsums   = (int*)  (ws + 110400064);      //        256 B

    hipMemsetAsync(counts, 0, 400000, stream);      // counts + fill

    int egrid = (EP + 255) / 256;
    k_hist      <<<egrid,       256, 0, stream>>>(ei, counts);
    k_scan_block<<<SCAN_BLOCKS, 256, 0, stream>>>(counts, row_ptr, bsums);
    k_scan_add  <<<SCAN_BLOCKS, 256, 0, stream>>>(row_ptr, bsums);
    k_scatter   <<<egrid,       256, 0, stream>>>(ei, row_ptr, fill, colb);

    k_cvtWfrag  <<<32,     256, 0, stream>>>(W1, Wfrag);
    k_gemm1m   <<<GM_GRID, 256, 0, stream>>>(x, Wfrag, xph, asrc1, adst1, as1T, ad1T);
    k_aggh     <<<100000,  256, 0, stream>>>((const uint2*)xph, as1T, ad1T, row_ptr, colb,
                                             b1, W2, hpart);
    k_post     <<<196,     256, 0, stream>>>(hpart, asrc2, adst2, xp2, as2, ad2);
    k_agg2     <<<3125,    256, 0, stream>>>(xp2, as2, ad2, row_ptr, colb, b2, out);
}

// Round 3
// 324.581 us; speedup vs baseline: 1.1428x; 1.1428x over previous
//
#include <hip/hip_runtime.h>
#include <math.h>

#define N_NODES 50000
#define N_EDGES 800000
#define EP (N_EDGES + N_NODES)   // 850000 edges incl. self loops
#define NEG 0.2f
#define SCAN_BLOCKS 49           // ceil(50000/1024)
#define HB N_NODES               // nodes per head slice

typedef __attribute__((ext_vector_type(8))) short bf16x8;
typedef __attribute__((ext_vector_type(4))) float f32x4;
typedef __attribute__((ext_vector_type(2))) float f32x2;

// bf16 round-to-nearest-even from fp32
static __device__ __forceinline__ unsigned short bf16_rn(float f) {
    union { float f; unsigned int u; } v; v.f = f;
    unsigned int u = v.u;
    unsigned int r = (u + 0x7FFFu + ((u >> 16) & 1u)) >> 16;
    return (unsigned short)r;
}
// unpack 2 bf16 (packed in a dword) -> f32x2 {low, high}
static __device__ __forceinline__ f32x2 bf2_unpack(unsigned int u) {
    union { unsigned int i; float f; } a, b;
    a.i = u << 16; b.i = u & 0xFFFF0000u;
    return (f32x2){a.f, b.f};
}

// ---------------- CSR build ----------------

__global__ void k_hist(const int* __restrict__ ei, int* __restrict__ counts) {
    int e = blockIdx.x * 256 + threadIdx.x;
    if (e >= EP) return;
    int d = (e < N_EDGES) ? ei[N_EDGES + e] : (e - N_EDGES);
    atomicAdd(&counts[d], 1);
}

__global__ void k_scan_block(const int* __restrict__ counts, int* __restrict__ excl,
                             int* __restrict__ bsums) {
    __shared__ int wsum[4];
    int b = blockIdx.x, t = threadIdx.x;
    int lane = t & 63, w = t >> 6;
    int i0 = b * 1024 + t * 4;
    int v0 = (i0 + 0 < N_NODES) ? counts[i0 + 0] : 0;
    int v1 = (i0 + 1 < N_NODES) ? counts[i0 + 1] : 0;
    int v2 = (i0 + 2 < N_NODES) ? counts[i0 + 2] : 0;
    int v3 = (i0 + 3 < N_NODES) ? counts[i0 + 3] : 0;
    int s = v0 + v1 + v2 + v3;
    int incl = s;
    #pragma unroll
    for (int d = 1; d < 64; d <<= 1) {
        int u = __shfl_up(incl, d);
        if (lane >= d) incl += u;
    }
    if (lane == 63) wsum[w] = incl;
    __syncthreads();
    if (t == 0) {
        int run = 0;
        #pragma unroll
        for (int i = 0; i < 4; ++i) { int x = wsum[i]; wsum[i] = run; run += x; }
        bsums[b] = run;   // block total
    }
    __syncthreads();
    int base = wsum[w] + incl - s;   // exclusive prefix of this thread's chunk
    if (i0 + 0 < N_NODES) excl[i0 + 0] = base;
    if (i0 + 1 < N_NODES) excl[i0 + 1] = base + v0;
    if (i0 + 2 < N_NODES) excl[i0 + 2] = base + v0 + v1;
    if (i0 + 3 < N_NODES) excl[i0 + 3] = base + v0 + v1 + v2;
}

// scan_mid folded in: every block wave-scans the 49 block sums itself
__global__ void k_scan_add(int* __restrict__ row_ptr, const int* __restrict__ bsums) {
    __shared__ int soff;
    int b = blockIdx.x, t = threadIdx.x;
    if (t < 64) {
        int v = (t < SCAN_BLOCKS) ? bsums[t] : 0;
        int incl = v;
        #pragma unroll
        for (int d = 1; d < 64; d <<= 1) {
            int u = __shfl_up(incl, d);
            if (t >= d) incl += u;
        }
        if (t == b) soff = incl - v;   // exclusive prefix at block b
    }
    __syncthreads();
    int off = soff;
    int i0 = b * 1024 + t * 4;
    #pragma unroll
    for (int j = 0; j < 4; ++j)
        if (i0 + j < N_NODES) row_ptr[i0 + j] += off;
    if (b == 0 && t == 0) row_ptr[N_NODES] = EP;
}

__global__ void k_scatter(const int* __restrict__ ei, const int* __restrict__ row_ptr,
                          int* __restrict__ fill, int* __restrict__ colb) {
    int e = blockIdx.x * 256 + threadIdx.x;
    if (e >= EP) return;
    int s, d;
    if (e < N_EDGES) { s = ei[e]; d = ei[N_EDGES + e]; }
    else             { s = e - N_EDGES; d = s; }
    int pos = row_ptr[d] + atomicAdd(&fill[d], 1);
    colb[pos] = s;
}

// ---------------- W1 -> MFMA B-fragment order (pi-permuted), bf16 ----------------
__global__ void k_cvtWfrag(const float* __restrict__ W1, bf16x8* __restrict__ Wfrag) {
    int ft = blockIdx.x * 256 + threadIdx.x;   // 8192 frag-lanes
    int c = ft >> 10, rem = ft & 1023;
    int nt = rem >> 6, l = rem & 63;
    int n = (l & 15) * 16 + nt;
    int k0 = c * 32 + (l >> 4) * 8;
    bf16x8 f;
    #pragma unroll
    for (int j = 0; j < 8; ++j)
        f[j] = (short)bf16_rn(W1[(k0 + j) * 256 + n]);
    Wfrag[ft] = f;
}

// ---------------- Layer 1 GEMM via bf16 MFMA + fused attention logits ----------------
// Output layout: head-major slices xph[h][node][32ch] bf16 (per-head 3.2MB working
// set fits one XCD's 4MB L2). as1/ad1 stored transposed: as1T[h][node].
#define GM_GRID 782   // ceil(50000/64)
__global__ __launch_bounds__(256) void
k_gemm1m(const float* __restrict__ x, const bf16x8* __restrict__ Wfrag,
         unsigned short* __restrict__ xph,
         const float* __restrict__ asrc, const float* __restrict__ adst,
         float* __restrict__ as1T, float* __restrict__ ad1T) {
    __shared__ bf16x8 lds[1024];   // one chunk of B frags: 16 KB
    int t = threadIdx.x, l = t & 63, w = t >> 6;
    int rowbase = blockIdx.x * 64 + w * 16;
    int m = l & 15, kg = l >> 4;

    f32x4 acc[16];
    #pragma unroll
    for (int nt = 0; nt < 16; ++nt)
        acc[nt] = (f32x4){0.f, 0.f, 0.f, 0.f};

    int r0 = rowbase + m;
    if (r0 > N_NODES - 1) r0 = N_NODES - 1;   // clamp (results unused)
    const float4* x4 = (const float4*)x;

    for (int c = 0; c < 8; ++c) {
        __syncthreads();   // previous chunk's B reads done before overwrite
        const bf16x8* src = Wfrag + c * 1024;
        #pragma unroll
        for (int q = 0; q < 4; ++q)
            lds[q * 256 + t] = src[q * 256 + t];
        __syncthreads();

        int kb = (c * 32 + kg * 8) >> 2;       // float4 col index
        float4 xa0 = x4[r0 * 64 + kb], xb0 = x4[r0 * 64 + kb + 1];
        bf16x8 aF0;
        aF0[0] = (short)bf16_rn(xa0.x); aF0[1] = (short)bf16_rn(xa0.y);
        aF0[2] = (short)bf16_rn(xa0.z); aF0[3] = (short)bf16_rn(xa0.w);
        aF0[4] = (short)bf16_rn(xb0.x); aF0[5] = (short)bf16_rn(xb0.y);
        aF0[6] = (short)bf16_rn(xb0.z); aF0[7] = (short)bf16_rn(xb0.w);

        #pragma unroll
        for (int nt = 0; nt < 16; ++nt) {
            bf16x8 bF = lds[nt * 64 + l];
            acc[nt] = __builtin_amdgcn_mfma_f32_16x16x32_bf16(aF0, bF, acc[nt], 0, 0, 0);
        }
    }

    // epilogue: lane holds channels cbase*16 + nt (nt=0..15) of rows rq*4+reg
    int cbase = l & 15, rq = l >> 4;
    int head = cbase >> 1, hhalf = cbase & 1;   // 16-ch half within head
    float asV[16], adV[16];
    #pragma unroll
    for (int q = 0; q < 4; ++q) {
        float4 sa = ((const float4*)asrc)[cbase * 4 + q];
        float4 da = ((const float4*)adst)[cbase * 4 + q];
        asV[q * 4 + 0] = sa.x; asV[q * 4 + 1] = sa.y; asV[q * 4 + 2] = sa.z; asV[q * 4 + 3] = sa.w;
        adV[q * 4 + 0] = da.x; adV[q * 4 + 1] = da.y; adV[q * 4 + 2] = da.z; adV[q * 4 + 3] = da.w;
    }
    #pragma unroll
    for (int reg = 0; reg < 4; ++reg) {
        int gr = rowbase + rq * 4 + reg;
        unsigned int ob[8];
        float ps = 0.f, pd = 0.f;
        #pragma unroll
        for (int q = 0; q < 8; ++q) {
            float v0 = acc[2 * q][reg], v1 = acc[2 * q + 1][reg];
            ob[q] = (unsigned int)bf16_rn(v0) | ((unsigned int)bf16_rn(v1) << 16);
            ps = fmaf(v0, asV[2 * q], ps);     ps = fmaf(v1, asV[2 * q + 1], ps);
            pd = fmaf(v0, adV[2 * q], pd);     pd = fmaf(v1, adV[2 * q + 1], pd);
        }
        ps += __shfl_xor(ps, 1);
        pd += __shfl_xor(pd, 1);
        if (gr < N_NODES) {
            // head-major slice write: [head][node][32ch], this lane's 16-ch half
            uint4* dst = (uint4*)(xph + (head * HB + gr) * 32 + hhalf * 16);
            dst[0] = make_uint4(ob[0], ob[1], ob[2], ob[3]);
            dst[1] = make_uint4(ob[4], ob[5], ob[6], ob[7]);
            if (hhalf == 0) {
                as1T[head * HB + gr] = ps;
                ad1T[head * HB + gr] = pd;
            }
        }
    }
}

// ---------------- head-sliced layer-1 softmax-aggregate + ReLU + proj2 partial ----
// head = blockIdx.x & 7 (XCD-pinned: per-head 3.4MB hot set is L2-resident).
// Lane = (node, ch-sub): 64 lanes = 16 nodes x 4 subs, sub owns 8 channels
// (uint4, 16B; 4 contiguous lanes fetch an edge's full 64B row). Each lane walks
// its node's ENTIRE edge list (software-pipelined 1-ahead), so accumulators and
// den need NO cross-lane reduction; only the 2-element proj2 dot reduces (2 shfl).
#define AGH_GRID (782 * 8)   // 782 blocks/head (64 nodes each) x 8 heads
__global__ __launch_bounds__(256) void
k_aggh(const uint4* __restrict__ xph4, const float* __restrict__ as1T,
       const float* __restrict__ ad1T, const int* __restrict__ row_ptr,
       const int* __restrict__ colb, const float* __restrict__ b1,
       const float* __restrict__ W2, float2* __restrict__ hpart) {
    int t = threadIdx.x, l = t & 63, w = t >> 6;
    int bid = blockIdx.x;
    int h = bid & 7;                    // XCD-pinned head
    int g = bid >> 3;                   // node-group 0..781
    int node = g * 64 + w * 16 + (l >> 2);
    int sub = l & 3;                    // channels h*32 + sub*8 .. +7
    bool alive = node < N_NODES;
    int nc = alive ? node : (N_NODES - 1);
    int start = row_ptr[nc], end = row_ptr[nc + 1];
    if (!alive) end = start;
    float adn = ad1T[h * HB + nc];
    const float* asb = as1T + h * HB;
    const uint4* xb = xph4 + (size_t)h * (HB * 4);

    f32x2 a0 = {0.f, 0.f}, a1 = {0.f, 0.f}, a2 = {0.f, 0.f}, a3 = {0.f, 0.f};
    float den = 0.f;

    int j = start;
    if (j < end) {
        int s = colb[j];
        float av = asb[s];
        uint4 r = xb[s * 4 + sub];
        for (++j; j < end; ++j) {
            // prefetch next edge while accumulating current one
            int s2 = colb[j];
            float av2 = asb[s2];
            uint4 r2 = xb[s2 * 4 + sub];
            float e = av + adn;
            e = (e > 0.f) ? e : NEG * e;
            float p = __expf(e);
            den += p;
            f32x2 q = {p, p};
            a0 += q * bf2_unpack(r.x);
            a1 += q * bf2_unpack(r.y);
            a2 += q * bf2_unpack(r.z);
            a3 += q * bf2_unpack(r.w);
            av = av2; r = r2;
        }
        float e = av + adn;
        e = (e > 0.f) ? e : NEG * e;
        float p = __expf(e);
        den += p;
        f32x2 q = {p, p};
        a0 += q * bf2_unpack(r.x);
        a1 += q * bf2_unpack(r.y);
        a2 += q * bf2_unpack(r.z);
        a3 += q * bf2_unpack(r.w);
    }

    // epilogue: softmax-normalize, +bias, ReLU, proj2 partial for this head
    float inv = 1.f / den;               // den>0 (self-loop guaranteed)
    const float4* b4 = (const float4*)b1;
    float4 ba = b4[h * 8 + sub * 2 + 0];
    float4 bb = b4[h * 8 + sub * 2 + 1];
    float o0 = fmaxf(fmaf(a0[0], inv, ba.x), 0.f);
    float o1 = fmaxf(fmaf(a0[1], inv, ba.y), 0.f);
    float o2 = fmaxf(fmaf(a1[0], inv, ba.z), 0.f);
    float o3 = fmaxf(fmaf(a1[1], inv, ba.w), 0.f);
    float o4 = fmaxf(fmaf(a2[0], inv, bb.x), 0.f);
    float o5 = fmaxf(fmaf(a2[1], inv, bb.y), 0.f);
    float o6 = fmaxf(fmaf(a3[0], inv, bb.z), 0.f);
    float o7 = fmaxf(fmaf(a3[1], inv, bb.w), 0.f);
    // W2 row-major (256,2): rows rb = h*32 + sub*8 .. +7; float4 = 2 rows
    const float4* W4 = (const float4*)W2;
    float4 wA = W4[h * 16 + sub * 4 + 0];
    float4 wB = W4[h * 16 + sub * 4 + 1];
    float4 wC = W4[h * 16 + sub * 4 + 2];
    float4 wD = W4[h * 16 + sub * 4 + 3];
    float d0 = o0 * wA.x + o1 * wA.z + o2 * wB.x + o3 * wB.z
             + o4 * wC.x + o5 * wC.z + o6 * wD.x + o7 * wD.z;
    float d1 = o0 * wA.y + o1 * wA.w + o2 * wB.y + o3 * wB.w
             + o4 * wC.y + o5 * wC.w + o6 * wD.y + o7 * wD.w;
    // reduce across the node's 4 subs (lanes 4n..4n+3)
    d0 += __shfl_xor(d0, 1);  d0 += __shfl_xor(d0, 2);
    d1 += __shfl_xor(d1, 1);  d1 += __shfl_xor(d1, 2);
    if (sub == 0 && alive)
        hpart[node * 8 + h] = (float2){d0, d1};
}

// ---------------- sum head partials -> xp2 / layer-2 logits ----------------
__global__ void k_post(const float2* __restrict__ hpart, const float* __restrict__ as2w,
                       const float* __restrict__ ad2w, float* __restrict__ xp2,
                       float* __restrict__ as2, float* __restrict__ ad2) {
    int n = blockIdx.x * 256 + threadIdx.x;
    if (n >= N_NODES) return;
    const float4* hp4 = (const float4*)(hpart + n * 8);
    float d0 = 0.f, d1 = 0.f;
    #pragma unroll
    for (int q = 0; q < 4; ++q) {
        float4 v = hp4[q];
        d0 += v.x + v.z;
        d1 += v.y + v.w;
    }
    xp2[2 * n] = d0;
    xp2[2 * n + 1] = d1;
    as2[n] = d0 * as2w[0] + d1 * as2w[1];
    ad2[n] = d0 * ad2w[0] + d1 * ad2w[1];
}

// ---------------- fused segment-softmax + aggregate, layer 2 (2 channels) ----------------
__global__ void k_agg2(const float* __restrict__ xp2, const float* __restrict__ as2,
                       const float* __restrict__ ad2, const int* __restrict__ row_ptr,
                       const int* __restrict__ colb, const float* __restrict__ b2,
                       float* __restrict__ out) {
    int t = threadIdx.x;
    int g = t >> 4, lane = t & 15;
    int n = blockIdx.x * 16 + g;
    int start = row_ptr[n], end = row_ptr[n + 1];
    float adn = ad2[n];
    float a0 = 0.f, a1 = 0.f, den = 0.f;
    for (int j = start + lane; j < end; j += 16) {
        int s = colb[j];
        float e = as2[s] + adn;
        e = (e > 0.f) ? e : NEG * e;
        float p = __expf(e);
        den += p;
        float2 xv = ((const float2*)xp2)[s];
        a0 = fmaf(p, xv.x, a0);
        a1 = fmaf(p, xv.y, a1);
    }
    #pragma unroll
    for (int m = 1; m < 16; m <<= 1) {
        a0 += __shfl_xor(a0, m);
        a1 += __shfl_xor(a1, m);
        den += __shfl_xor(den, m);
    }
    if (lane == 0) {
        out[2 * n] = a0 / den + b2[0];
        out[2 * n + 1] = a1 / den + b2[1];
    }
}

extern "C" void kernel_launch(void* const* d_in, const int* in_sizes, int n_in,
                              void* d_out, int out_size, void* d_ws, size_t ws_size,
                              hipStream_t stream) {
    const float* x     = (const float*)d_in[0];
    const int*   ei    = (const int*)d_in[1];
    const float* W1    = (const float*)d_in[2];
    const float* asrc1 = (const float*)d_in[3];
    const float* adst1 = (const float*)d_in[4];
    const float* b1    = (const float*)d_in[5];
    const float* W2    = (const float*)d_in[6];
    const float* asrc2 = (const float*)d_in[7];
    const float* adst2 = (const float*)d_in[8];
    const float* b2    = (const float*)d_in[9];
    float* out = (float*)d_out;

    char* ws = (char*)d_ws;
    unsigned short* xph = (unsigned short*)(ws + 0);  // 25,600,000 B (bf16, head-major)
    bf16x8* Wfrag  = (bf16x8*)(ws + 25600000);      //    131,072 B (B frags)
    float2* hpart  = (float2*)(ws + 25800000);      //  3,200,000 B (per-head proj2 partials)
    float* as1T    = (float*)(ws + 102400000);      //  1,600,000 B ([8][50000])
    float* ad1T    = (float*)(ws + 104000000);      //  1,600,000 B ([8][50000])
    float* xp2     = (float*)(ws + 105600000);      //    400,000 B
    float* as2     = (float*)(ws + 106000000);      //    200,000 B
    float* ad2     = (float*)(ws + 106200000);      //    200,000 B
    int*   counts  = (int*)  (ws + 106400000);      //    200,000 B
    int*   fill    = (int*)  (ws + 106600000);      //    200,000 B (contig w/ counts)
    int*   row_ptr = (int*)  (ws + 106800000);      //    200,064 B
    int*   colb    = (int*)  (ws + 107000064);      //  3,400,000 B
    int*   bsums   = (int*)  (ws + 110400064);      //        256 B

    hipMemsetAsync(counts, 0, 400000, stream);      // counts + fill

    int egrid = (EP + 255) / 256;
    k_hist      <<<egrid,       256, 0, stream>>>(ei, counts);
    k_scan_block<<<SCAN_BLOCKS, 256, 0, stream>>>(counts, row_ptr, bsums);
    k_scan_add  <<<SCAN_BLOCKS, 256, 0, stream>>>(row_ptr, bsums);
    k_scatter   <<<egrid,       256, 0, stream>>>(ei, row_ptr, fill, colb);

    k_cvtWfrag  <<<32,     256, 0, stream>>>(W1, Wfrag);
    k_gemm1m   <<<GM_GRID, 256, 0, stream>>>(x, Wfrag, xph, asrc1, adst1, as1T, ad1T);
    k_aggh     <<<AGH_GRID, 256, 0, stream>>>((const uint4*)xph, as1T, ad1T, row_ptr, colb,
                                              b1, W2, hpart);
    k_post     <<<196,     256, 0, stream>>>(hpart, asrc2, adst2, xp2, as2, ad2);
    k_agg2     <<<3125,    256, 0, stream>>>(xp2, as2, ad2, row_ptr, colb, b2, out);
}

// Round 4
// 297.840 us; speedup vs baseline: 1.2454x; 1.0898x over previous
//
#include <hip/hip_runtime.h>
#include <math.h>

#define N_NODES 50000
#define N_EDGES 800000
#define EP (N_EDGES + N_NODES)   // 850000 edges incl. self loops
#define NEG 0.2f
#define SCAN_BLOCKS 49           // ceil(50000/1024)
#define HB N_NODES               // nodes per head slice

typedef __attribute__((ext_vector_type(8))) short bf16x8;
typedef __attribute__((ext_vector_type(4))) float f32x4;
typedef __attribute__((ext_vector_type(2))) float f32x2;

// bf16 round-to-nearest-even from fp32
static __device__ __forceinline__ unsigned short bf16_rn(float f) {
    union { float f; unsigned int u; } v; v.f = f;
    unsigned int u = v.u;
    unsigned int r = (u + 0x7FFFu + ((u >> 16) & 1u)) >> 16;
    return (unsigned short)r;
}
// unpack 2 bf16 (packed in a dword) -> f32x2 {low, high}
static __device__ __forceinline__ f32x2 bf2_unpack(unsigned int u) {
    union { unsigned int i; float f; } a, b;
    a.i = u << 16; b.i = u & 0xFFFF0000u;
    return (f32x2){a.f, b.f};
}

// ---------------- CSR build ----------------

__global__ void k_hist(const int* __restrict__ ei, int* __restrict__ counts) {
    int e = blockIdx.x * 256 + threadIdx.x;
    if (e >= EP) return;
    int d = (e < N_EDGES) ? ei[N_EDGES + e] : (e - N_EDGES);
    atomicAdd(&counts[d], 1);
}

__global__ void k_scan_block(const int* __restrict__ counts, int* __restrict__ excl,
                             int* __restrict__ bsums) {
    __shared__ int wsum[4];
    int b = blockIdx.x, t = threadIdx.x;
    int lane = t & 63, w = t >> 6;
    int i0 = b * 1024 + t * 4;
    int v0 = (i0 + 0 < N_NODES) ? counts[i0 + 0] : 0;
    int v1 = (i0 + 1 < N_NODES) ? counts[i0 + 1] : 0;
    int v2 = (i0 + 2 < N_NODES) ? counts[i0 + 2] : 0;
    int v3 = (i0 + 3 < N_NODES) ? counts[i0 + 3] : 0;
    int s = v0 + v1 + v2 + v3;
    int incl = s;
    #pragma unroll
    for (int d = 1; d < 64; d <<= 1) {
        int u = __shfl_up(incl, d);
        if (lane >= d) incl += u;
    }
    if (lane == 63) wsum[w] = incl;
    __syncthreads();
    if (t == 0) {
        int run = 0;
        #pragma unroll
        for (int i = 0; i < 4; ++i) { int x = wsum[i]; wsum[i] = run; run += x; }
        bsums[b] = run;   // block total
    }
    __syncthreads();
    int base = wsum[w] + incl - s;   // exclusive prefix of this thread's chunk
    if (i0 + 0 < N_NODES) excl[i0 + 0] = base;
    if (i0 + 1 < N_NODES) excl[i0 + 1] = base + v0;
    if (i0 + 2 < N_NODES) excl[i0 + 2] = base + v0 + v1;
    if (i0 + 3 < N_NODES) excl[i0 + 3] = base + v0 + v1 + v2;
}

// scan_mid folded in: every block wave-scans the 49 block sums itself
__global__ void k_scan_add(int* __restrict__ row_ptr, const int* __restrict__ bsums) {
    __shared__ int soff;
    int b = blockIdx.x, t = threadIdx.x;
    if (t < 64) {
        int v = (t < SCAN_BLOCKS) ? bsums[t] : 0;
        int incl = v;
        #pragma unroll
        for (int d = 1; d < 64; d <<= 1) {
            int u = __shfl_up(incl, d);
            if (t >= d) incl += u;
        }
        if (t == b) soff = incl - v;   // exclusive prefix at block b
    }
    __syncthreads();
    int off = soff;
    int i0 = b * 1024 + t * 4;
    #pragma unroll
    for (int j = 0; j < 4; ++j)
        if (i0 + j < N_NODES) row_ptr[i0 + j] += off;
    if (b == 0 && t == 0) row_ptr[N_NODES] = EP;
}

__global__ void k_scatter(const int* __restrict__ ei, const int* __restrict__ row_ptr,
                          int* __restrict__ fill, int* __restrict__ colb) {
    int e = blockIdx.x * 256 + threadIdx.x;
    if (e >= EP) return;
    int s, d;
    if (e < N_EDGES) { s = ei[e]; d = ei[N_EDGES + e]; }
    else             { s = e - N_EDGES; d = s; }
    int pos = row_ptr[d] + atomicAdd(&fill[d], 1);
    colb[pos] = s;
}

// ---------------- W1 -> MFMA B-fragment order (pi-permuted), bf16 ----------------
__global__ void k_cvtWfrag(const float* __restrict__ W1, bf16x8* __restrict__ Wfrag) {
    int ft = blockIdx.x * 256 + threadIdx.x;   // 8192 frag-lanes
    int c = ft >> 10, rem = ft & 1023;
    int nt = rem >> 6, l = rem & 63;
    int n = (l & 15) * 16 + nt;
    int k0 = c * 32 + (l >> 4) * 8;
    bf16x8 f;
    #pragma unroll
    for (int j = 0; j < 8; ++j)
        f[j] = (short)bf16_rn(W1[(k0 + j) * 256 + n]);
    Wfrag[ft] = f;
}

// ---------------- Layer 1 GEMM via bf16 MFMA + fused attention logits ----------------
// Output layout: head-major slices xph[h][node][32ch] bf16 (per-head 3.2MB working
// set fits one XCD's 4MB L2). as1/ad1 stored transposed: as1T[h][node].
#define GM_GRID 782   // ceil(50000/64)
__global__ __launch_bounds__(256) void
k_gemm1m(const float* __restrict__ x, const bf16x8* __restrict__ Wfrag,
         unsigned short* __restrict__ xph,
         const float* __restrict__ asrc, const float* __restrict__ adst,
         float* __restrict__ as1T, float* __restrict__ ad1T) {
    __shared__ bf16x8 lds[1024];   // one chunk of B frags: 16 KB
    int t = threadIdx.x, l = t & 63, w = t >> 6;
    int rowbase = blockIdx.x * 64 + w * 16;
    int m = l & 15, kg = l >> 4;

    f32x4 acc[16];
    #pragma unroll
    for (int nt = 0; nt < 16; ++nt)
        acc[nt] = (f32x4){0.f, 0.f, 0.f, 0.f};

    int r0 = rowbase + m;
    if (r0 > N_NODES - 1) r0 = N_NODES - 1;   // clamp (results unused)
    const float4* x4 = (const float4*)x;

    for (int c = 0; c < 8; ++c) {
        __syncthreads();   // previous chunk's B reads done before overwrite
        const bf16x8* src = Wfrag + c * 1024;
        #pragma unroll
        for (int q = 0; q < 4; ++q)
            lds[q * 256 + t] = src[q * 256 + t];
        __syncthreads();

        int kb = (c * 32 + kg * 8) >> 2;       // float4 col index
        float4 xa0 = x4[r0 * 64 + kb], xb0 = x4[r0 * 64 + kb + 1];
        bf16x8 aF0;
        aF0[0] = (short)bf16_rn(xa0.x); aF0[1] = (short)bf16_rn(xa0.y);
        aF0[2] = (short)bf16_rn(xa0.z); aF0[3] = (short)bf16_rn(xa0.w);
        aF0[4] = (short)bf16_rn(xb0.x); aF0[5] = (short)bf16_rn(xb0.y);
        aF0[6] = (short)bf16_rn(xb0.z); aF0[7] = (short)bf16_rn(xb0.w);

        #pragma unroll
        for (int nt = 0; nt < 16; ++nt) {
            bf16x8 bF = lds[nt * 64 + l];
            acc[nt] = __builtin_amdgcn_mfma_f32_16x16x32_bf16(aF0, bF, acc[nt], 0, 0, 0);
        }
    }

    // epilogue: lane holds channels cbase*16 + nt (nt=0..15) of rows rq*4+reg
    int cbase = l & 15, rq = l >> 4;
    int head = cbase >> 1, hhalf = cbase & 1;   // 16-ch half within head
    float asV[16], adV[16];
    #pragma unroll
    for (int q = 0; q < 4; ++q) {
        float4 sa = ((const float4*)asrc)[cbase * 4 + q];
        float4 da = ((const float4*)adst)[cbase * 4 + q];
        asV[q * 4 + 0] = sa.x; asV[q * 4 + 1] = sa.y; asV[q * 4 + 2] = sa.z; asV[q * 4 + 3] = sa.w;
        adV[q * 4 + 0] = da.x; adV[q * 4 + 1] = da.y; adV[q * 4 + 2] = da.z; adV[q * 4 + 3] = da.w;
    }
    #pragma unroll
    for (int reg = 0; reg < 4; ++reg) {
        int gr = rowbase + rq * 4 + reg;
        unsigned int ob[8];
        float ps = 0.f, pd = 0.f;
        #pragma unroll
        for (int q = 0; q < 8; ++q) {
            float v0 = acc[2 * q][reg], v1 = acc[2 * q + 1][reg];
            ob[q] = (unsigned int)bf16_rn(v0) | ((unsigned int)bf16_rn(v1) << 16);
            ps = fmaf(v0, asV[2 * q], ps);     ps = fmaf(v1, asV[2 * q + 1], ps);
            pd = fmaf(v0, adV[2 * q], pd);     pd = fmaf(v1, adV[2 * q + 1], pd);
        }
        ps += __shfl_xor(ps, 1);
        pd += __shfl_xor(pd, 1);
        if (gr < N_NODES) {
            // head-major slice write: [head][node][32ch], this lane's 16-ch half
            uint4* dst = (uint4*)(xph + (head * HB + gr) * 32 + hhalf * 16);
            dst[0] = make_uint4(ob[0], ob[1], ob[2], ob[3]);
            dst[1] = make_uint4(ob[4], ob[5], ob[6], ob[7]);
            if (hhalf == 0) {
                as1T[head * HB + gr] = ps;
                ad1T[head * HB + gr] = pd;
            }
        }
    }
}

// ---------------- head-sliced layer-1 softmax-aggregate + ReLU + proj2 partial ----
// head = blockIdx.x & 7 (XCD-pinned: per-head 3.4MB hot set is L2-resident).
// Lane = (node, ch-sub): 64 lanes = 16 nodes x 4 subs. QUAD-EDGE COOPERATION:
// per iteration the node's 4 lanes process 4 edges: lane sub loads colb[j+sub]
// (coalesced) + as1T gather + exp for ITS edge only, then each edge's (s,p) is
// quad-broadcast (2 shfl) and all 4 lanes apply the 64B row. Requests/edge drop
// 3 -> 2.25 and exposed colb->as latency steps drop 4x. den is quad-reduced.
#define AGH_GRID (782 * 8)   // 782 blocks/head (64 nodes each) x 8 heads
__global__ __launch_bounds__(256) void
k_aggh(const uint4* __restrict__ xph4, const float* __restrict__ as1T,
       const float* __restrict__ ad1T, const int* __restrict__ row_ptr,
       const int* __restrict__ colb, const float* __restrict__ b1,
       const float* __restrict__ W2, float2* __restrict__ hpart) {
    int t = threadIdx.x, l = t & 63, w = t >> 6;
    int bid = blockIdx.x;
    int h = bid & 7;                    // XCD-pinned head
    int g = bid >> 3;                   // node-group 0..781
    int node = g * 64 + w * 16 + (l >> 2);
    int sub = l & 3;                    // channels h*32 + sub*8 .. +7
    int qb = l & 60;                    // quad base lane
    bool alive = node < N_NODES;
    int nc = alive ? node : (N_NODES - 1);
    int start = row_ptr[nc], end = row_ptr[nc + 1];
    if (!alive) end = start;
    float adn = ad1T[h * HB + nc];
    const float* asb = as1T + h * HB;
    const uint4* xb = xph4 + (size_t)h * (HB * 4);

    f32x2 a0 = {0.f, 0.f}, a1 = {0.f, 0.f}, a2 = {0.f, 0.f}, a3 = {0.f, 0.f};
    float den = 0.f;

    int j = start;
    int s_pf = 0; float av_pf = 0.f; bool v_pf = false;
    if (j < end) {                      // uniform within the quad
        int jj = j + sub;
        v_pf = jj < end;
        s_pf = colb[v_pf ? jj : (end - 1)];
        av_pf = asb[s_pf];
    }
    while (j < end) {
        int s_cur = s_pf; float av_cur = av_pf; bool v_cur = v_pf;
        j += 4;
        if (j < end) {                  // prefetch next quad of edges
            int jj = j + sub;
            v_pf = jj < end;
            s_pf = colb[v_pf ? jj : (end - 1)];
            av_pf = asb[s_pf];
        }
        float e = av_cur + adn;
        e = (e > 0.f) ? e : NEG * e;
        float p = v_cur ? __expf(e) : 0.f;
        den += p;                        // own quarter only; quad-reduced later
        #pragma unroll
        for (int eidx = 0; eidx < 4; ++eidx) {
            int   se = __shfl(s_cur, qb + eidx);
            float pe = __shfl(p,     qb + eidx);
            uint4 r = xb[(size_t)se * 4 + sub];
            f32x2 q = {pe, pe};
            a0 += q * bf2_unpack(r.x);
            a1 += q * bf2_unpack(r.y);
            a2 += q * bf2_unpack(r.z);
            a3 += q * bf2_unpack(r.w);
        }
    }
    // quad-reduce den (accumulators already see every edge)
    den += __shfl_xor(den, 1);
    den += __shfl_xor(den, 2);

    // epilogue: softmax-normalize, +bias, ReLU, proj2 partial for this head
    float inv = 1.f / den;               // den>0 (self-loop guaranteed)
    const float4* b4 = (const float4*)b1;
    float4 ba = b4[h * 8 + sub * 2 + 0];
    float4 bb = b4[h * 8 + sub * 2 + 1];
    float o0 = fmaxf(fmaf(a0[0], inv, ba.x), 0.f);
    float o1 = fmaxf(fmaf(a0[1], inv, ba.y), 0.f);
    float o2 = fmaxf(fmaf(a1[0], inv, ba.z), 0.f);
    float o3 = fmaxf(fmaf(a1[1], inv, ba.w), 0.f);
    float o4 = fmaxf(fmaf(a2[0], inv, bb.x), 0.f);
    float o5 = fmaxf(fmaf(a2[1], inv, bb.y), 0.f);
    float o6 = fmaxf(fmaf(a3[0], inv, bb.z), 0.f);
    float o7 = fmaxf(fmaf(a3[1], inv, bb.w), 0.f);
    // W2 row-major (256,2): rows rb = h*32 + sub*8 .. +7; float4 = 2 rows
    const float4* W4 = (const float4*)W2;
    float4 wA = W4[h * 16 + sub * 4 + 0];
    float4 wB = W4[h * 16 + sub * 4 + 1];
    float4 wC = W4[h * 16 + sub * 4 + 2];
    float4 wD = W4[h * 16 + sub * 4 + 3];
    float d0 = o0 * wA.x + o1 * wA.z + o2 * wB.x + o3 * wB.z
             + o4 * wC.x + o5 * wC.z + o6 * wD.x + o7 * wD.z;
    float d1 = o0 * wA.y + o1 * wA.w + o2 * wB.y + o3 * wB.w
             + o4 * wC.y + o5 * wC.w + o6 * wD.y + o7 * wD.w;
    // reduce across the node's 4 subs (lanes 4n..4n+3)
    d0 += __shfl_xor(d0, 1);  d0 += __shfl_xor(d0, 2);
    d1 += __shfl_xor(d1, 1);  d1 += __shfl_xor(d1, 2);
    if (sub == 0 && alive)
        hpart[node * 8 + h] = (float2){d0, d1};
}

// ---------------- sum head partials -> packed layer-2 record ----------------
// pk[n] = {xp2.x, xp2.y, as2, ad2}: one 16B gather per edge in k_agg2.
__global__ void k_post(const float2* __restrict__ hpart, const float* __restrict__ as2w,
                       const float* __restrict__ ad2w, float4* __restrict__ pk) {
    int n = blockIdx.x * 256 + threadIdx.x;
    if (n >= N_NODES) return;
    const float4* hp4 = (const float4*)(hpart + n * 8);
    float d0 = 0.f, d1 = 0.f;
    #pragma unroll
    for (int q = 0; q < 4; ++q) {
        float4 v = hp4[q];
        d0 += v.x + v.z;
        d1 += v.y + v.w;
    }
    float4 r;
    r.x = d0;
    r.y = d1;
    r.z = d0 * as2w[0] + d1 * as2w[1];   // as2
    r.w = d0 * ad2w[0] + d1 * ad2w[1];   // ad2
    pk[n] = r;
}

// ---------------- fused segment-softmax + aggregate, layer 2 (2 channels) ----------------
__global__ void k_agg2(const float4* __restrict__ pk, const int* __restrict__ row_ptr,
                       const int* __restrict__ colb, const float* __restrict__ b2,
                       float* __restrict__ out) {
    int t = threadIdx.x;
    int g = t >> 4, lane = t & 15;
    int n = blockIdx.x * 16 + g;
    int start = row_ptr[n], end = row_ptr[n + 1];
    float adn = pk[n].w;
    float a0 = 0.f, a1 = 0.f, den = 0.f;
    for (int j = start + lane; j < end; j += 16) {
        int s = colb[j];
        float4 r = pk[s];
        float e = r.z + adn;
        e = (e > 0.f) ? e : NEG * e;
        float p = __expf(e);
        den += p;
        a0 = fmaf(p, r.x, a0);
        a1 = fmaf(p, r.y, a1);
    }
    #pragma unroll
    for (int m = 1; m < 16; m <<= 1) {
        a0 += __shfl_xor(a0, m);
        a1 += __shfl_xor(a1, m);
        den += __shfl_xor(den, m);
    }
    if (lane == 0) {
        out[2 * n] = a0 / den + b2[0];
        out[2 * n + 1] = a1 / den + b2[1];
    }
}

extern "C" void kernel_launch(void* const* d_in, const int* in_sizes, int n_in,
                              void* d_out, int out_size, void* d_ws, size_t ws_size,
                              hipStream_t stream) {
    const float* x     = (const float*)d_in[0];
    const int*   ei    = (const int*)d_in[1];
    const float* W1    = (const float*)d_in[2];
    const float* asrc1 = (const float*)d_in[3];
    const float* adst1 = (const float*)d_in[4];
    const float* b1    = (const float*)d_in[5];
    const float* W2    = (const float*)d_in[6];
    const float* asrc2 = (const float*)d_in[7];
    const float* adst2 = (const float*)d_in[8];
    const float* b2    = (const float*)d_in[9];
    float* out = (float*)d_out;

    char* ws = (char*)d_ws;
    unsigned short* xph = (unsigned short*)(ws + 0);  // 25,600,000 B (bf16, head-major)
    bf16x8* Wfrag  = (bf16x8*)(ws + 25600000);      //    131,072 B (B frags)
    float2* hpart  = (float2*)(ws + 25800000);      //  3,200,000 B (per-head proj2 partials)
    float* as1T    = (float*)(ws + 102400000);      //  1,600,000 B ([8][50000])
    float* ad1T    = (float*)(ws + 104000000);      //  1,600,000 B ([8][50000])
    float4* pk     = (float4*)(ws + 105600000);     //    800,000 B (packed layer-2 records)
    int*   counts  = (int*)  (ws + 106400000);      //    200,000 B
    int*   fill    = (int*)  (ws + 106600000);      //    200,000 B (contig w/ counts)
    int*   row_ptr = (int*)  (ws + 106800000);      //    200,064 B
    int*   colb    = (int*)  (ws + 107000064);      //  3,400,000 B
    int*   bsums   = (int*)  (ws + 110400064);      //        256 B

    hipMemsetAsync(counts, 0, 400000, stream);      // counts + fill

    int egrid = (EP + 255) / 256;
    k_hist      <<<egrid,       256, 0, stream>>>(ei, counts);
    k_scan_block<<<SCAN_BLOCKS, 256, 0, stream>>>(counts, row_ptr, bsums);
    k_scan_add  <<<SCAN_BLOCKS, 256, 0, stream>>>(row_ptr, bsums);
    k_scatter   <<<egrid,       256, 0, stream>>>(ei, row_ptr, fill, colb);

    k_cvtWfrag  <<<32,     256, 0, stream>>>(W1, Wfrag);
    k_gemm1m   <<<GM_GRID, 256, 0, stream>>>(x, Wfrag, xph, asrc1, adst1, as1T, ad1T);
    k_aggh     <<<AGH_GRID, 256, 0, stream>>>((const uint4*)xph, as1T, ad1T, row_ptr, colb,
                                              b1, W2, hpart);
    k_post     <<<196,     256, 0, stream>>>(hpart, asrc2, adst2, pk);
    k_agg2     <<<3125,    256, 0, stream>>>(pk, row_ptr, colb, b2, out);
}